// Round 12
// baseline (155.729 us; speedup 1.0000x reference)
//
#include <hip/hip_runtime.h>

typedef float  f32x16 __attribute__((ext_vector_type(16)));
typedef float  f32x2  __attribute__((ext_vector_type(2)));
typedef short  short8 __attribute__((ext_vector_type(8)));
typedef unsigned short u16;
typedef unsigned int   u32;

#define LOG2PI_F 1.8378770664093453f

__device__ __forceinline__ u16 f2bf(float f) {
  u32 u = __builtin_bit_cast(u32, f);
  u32 r = (u + 0x7FFFu + ((u >> 16) & 1u)) >> 16;
  return (u16)r;
}

// ---------------------------------------------------------------------------
// K0: emissions. E[t,j] = exp(log_em[t,j] - s_t), s_t = max_j log_em[t,j].
// ---------------------------------------------------------------------------
__global__ __launch_bounds__(256) void emis_kernel(
    const float* __restrict__ Y, const float* __restrict__ mu,
    const float* __restrict__ rlv, int T,
    float* __restrict__ E, float* __restrict__ Spart)
{
  int j  = threadIdx.x & 31;
  int ts = threadIdx.x >> 5;  // 0..7

  float muv[16], iv[16];
  float slv = 0.f;
  const float4* mp = (const float4*)(mu  + (size_t)j * 16);
  const float4* rp = (const float4*)(rlv + (size_t)j * 16);
#pragma unroll
  for (int q = 0; q < 4; ++q) {
    float4 m4 = mp[q], r4 = rp[q];
    float mm[4] = {m4.x, m4.y, m4.z, m4.w};
    float rr[4] = {r4.x, r4.y, r4.z, r4.w};
#pragma unroll
    for (int e = 0; e < 4; ++e) {
      float lv = fminf(fmaxf(rr[e], -6.f), 6.f);
      muv[4*q+e] = mm[e];
      iv[4*q+e]  = __expf(-lv);
      slv += lv;
    }
  }
  float base_c = 16.f * LOG2PI_F + slv;

  float sacc = 0.f;
  for (int p2 = 0; p2 < 8; ++p2) {
    int t = blockIdx.x * 64 + p2 * 8 + ts;
    if (t < T) {
      float quad = 0.f;
      const float4* yp = (const float4*)(Y + (size_t)t * 16);
#pragma unroll
      for (int q = 0; q < 4; ++q) {
        float4 y4 = yp[q];
        float yy[4] = {y4.x, y4.y, y4.z, y4.w};
#pragma unroll
        for (int e = 0; e < 4; ++e) {
          float d = yy[e] - muv[4*q+e];
          quad = fmaf(d * d, iv[4*q+e], quad);
        }
      }
      float lem = -0.5f * (base_c + quad);
      float mx = lem;
#pragma unroll
      for (int m = 16; m >= 1; m >>= 1) mx = fmaxf(mx, __shfl_xor(mx, m, 32));
      E[(size_t)t * 32 + j] = __expf(lem - mx);
      if (j == 0) sacc += mx;
    }
  }
  __shared__ float sred[8];
  if (j == 0) sred[ts] = sacc;
  __syncthreads();
  if (threadIdx.x == 0) {
    float s = 0.f;
#pragma unroll
    for (int k = 0; k < 8; ++k) s += sred[k];
    Spart[blockIdx.x] = s;
  }
}

// ---------------------------------------------------------------------------
// Prep: Wfrag = A-operand fragments of W/ln2 (bf16), bprime = b/ln2.
// ---------------------------------------------------------------------------
__global__ __launch_bounds__(256) void prep_kernel(
    const float* __restrict__ W, const float* __restrict__ b,
    u16* __restrict__ Wfrag, float* __restrict__ bprime)
{
  const float INVLN2 = 1.4426950408889634f;
  int idx = blockIdx.x * 256 + threadIdx.x;
  if (idx < 16384) {
    int i = idx >> 9, rem = idx & 511, l = rem >> 3, e = rem & 7;
    int j = l & 31, h = l >> 5;
    Wfrag[idx] = f2bf(W[i * 512 + j * 16 + h * 8 + e] * INVLN2);
  }
  if (idx < 1024) bprime[idx] = b[idx] * INVLN2;
}

// ---------------------------------------------------------------------------
// Shared primitives (hardware-verified rounds 0-11).
// ---------------------------------------------------------------------------
__device__ __forceinline__ void acc_to_bops(const f32x16& acc, uint4& B1, uint4& B2) {
  u32 pk[8];
#pragma unroll
  for (int q = 0; q < 8; ++q) {
    u32 r;
    asm("v_cvt_pk_bf16_f32 %0, %1, %2" : "=v"(r) : "v"(acc[2*q]), "v"(acc[2*q+1]));
    pk[q] = r;
  }
  asm("v_permlane32_swap_b32 %0, %1" : "+v"(pk[0]), "+v"(pk[2]));
  asm("v_permlane32_swap_b32 %0, %1" : "+v"(pk[1]), "+v"(pk[3]));
  B1 = make_uint4(pk[0], pk[1], pk[2], pk[3]);
  asm("v_permlane32_swap_b32 %0, %1" : "+v"(pk[4]), "+v"(pk[6]));
  asm("v_permlane32_swap_b32 %0, %1" : "+v"(pk[5]), "+v"(pk[7]));
  B2 = make_uint4(pk[4], pk[5], pk[6], pk[7]);
}

__device__ __forceinline__ void renorm(f32x16& acc, float& Eacc) {
  float m = acc[0];
#pragma unroll
  for (int r = 1; r < 16; ++r) m = fmaxf(m, acc[r]);
#pragma unroll
  for (int off = 32; off >= 1; off >>= 1) m = fmaxf(m, __shfl_xor(m, off, 64));
  if (m > 0.f) {
    int ex;
    frexpf(m, &ex);
    float sc = ldexpf(1.f, -ex);
#pragma unroll
    for (int r = 0; r < 16; ++r) acc[r] *= sc;
    Eacc += (float)ex;
  }
}

// fp8 chunk (8 e4m3 bytes in a uint2) -> 8 bf16 (uint4), byte order preserved.
__device__ __forceinline__ uint4 fp8x8_to_bf16x8(uint2 c) {
  f32x2 l0 = __builtin_amdgcn_cvt_pk_f32_fp8((int)c.x, false);
  f32x2 h0 = __builtin_amdgcn_cvt_pk_f32_fp8((int)c.x, true);
  f32x2 l1 = __builtin_amdgcn_cvt_pk_f32_fp8((int)c.y, false);
  f32x2 h1 = __builtin_amdgcn_cvt_pk_f32_fp8((int)c.y, true);
  u32 w0, w1, w2, w3;
  asm("v_cvt_pk_bf16_f32 %0, %1, %2" : "=v"(w0) : "v"(l0.x), "v"(l0.y));
  asm("v_cvt_pk_bf16_f32 %0, %1, %2" : "=v"(w1) : "v"(h0.x), "v"(h0.y));
  asm("v_cvt_pk_bf16_f32 %0, %1, %2" : "=v"(w2) : "v"(l1.x), "v"(l1.y));
  asm("v_cvt_pk_bf16_f32 %0, %1, %2" : "=v"(w3) : "v"(h1.x), "v"(h1.y));
  return make_uint4(w0, w1, w2, w3);
}

// ---------------------------------------------------------------------------
// Production batch (verified math), output packed fp8 SCALED BY 2^7:
// q[r] = 4 e4m3 bytes = 128*B[t=tc][i=ib0..ib0+3][j(r,h)]. The 2^7 per-matrix
// scale is absorbed by the chain's power-of-2 renorm into Eacc and removed
// once in finalize (Egrand - 7*T). ee[] arrives pre-scaled by 128.
// Softmax sum is a depth-4 tree (f32 reassociation only).
// ---------------------------------------------------------------------------
__device__ __forceinline__ void bmat2_batch_fp8(
    const short8* wf, int ib0, short8 xf, const float* __restrict__ bprime,
    int h, const float* ee, int tglob, u32* q /* [16] */)
{
  f32x16 a[4];
#pragma unroll
  for (int e = 0; e < 4; ++e) {
    f32x16 c;
#pragma unroll
    for (int qd = 0; qd < 4; ++qd) {
      float4 b4 = *(const float4*)(bprime + (ib0 + e) * 32 + 4 * h + 8 * qd);
      c[4*qd+0] = b4.x; c[4*qd+1] = b4.y; c[4*qd+2] = b4.z; c[4*qd+3] = b4.w;
    }
    a[e] = __builtin_amdgcn_mfma_f32_32x32x16_bf16(wf[e], xf, c, 0, 0, 0);
  }
#pragma unroll
  for (int e = 0; e < 4; ++e) {
#pragma unroll
    for (int r = 0; r < 16; ++r) a[e][r] = exp2f(a[e][r]);
    float s = (((a[e][0] + a[e][1]) + (a[e][2] + a[e][3])) +
               ((a[e][4] + a[e][5]) + (a[e][6] + a[e][7]))) +
              (((a[e][8] + a[e][9]) + (a[e][10] + a[e][11])) +
               ((a[e][12] + a[e][13]) + (a[e][14] + a[e][15])));
    float s2 = s, s3 = s;
    asm("v_permlane32_swap_b32 %0, %1" : "+v"(s2), "+v"(s3));
    float rv = __builtin_amdgcn_rcpf(s2 + s3);
#pragma unroll
    for (int r = 0; r < 16; ++r) a[e][r] *= rv;
  }
#pragma unroll
  for (int r = 0; r < 16; ++r) {
    float e0 = a[0][r] * ee[r], e1 = a[1][r] * ee[r];
    float e2 = a[2][r] * ee[r], e3 = a[3][r] * ee[r];
    if (tglob == 0) {
      int j = 4 * h + 8 * (r >> 2) + (r & 3);
      e0 = (ib0 + 0 == j) ? 128.f : 0.f;   // scaled identity, exact in e4m3
      e1 = (ib0 + 1 == j) ? 128.f : 0.f;
      e2 = (ib0 + 2 == j) ? 128.f : 0.f;
      e3 = (ib0 + 3 == j) ? 128.f : 0.f;
    }
    u32 v = (u32)__builtin_amdgcn_cvt_pk_fp8_f32(e0, e1, 0, false);
    v = (u32)__builtin_amdgcn_cvt_pk_fp8_f32(e2, e3, (int)v, true);
    q[r] = v;
  }
}

// ---------------------------------------------------------------------------
// fused1w: ONE WAVE per block (r8-r11-green structure), block owns 64 t.
// fp8 staging (32KB) scaled by 2^7; chunk-index XOR swizzle (c ^ (tc&15)).
// Chain phase: software-prefetched A (LDS read + upconvert hoisted above the
// acc-dependent B-prep) and two INDEPENDENT MFMAs + f32 add per step (halves
// the serial MFMA depth). Math identical up to f32 reassociation.
// ---------------------------------------------------------------------------
__global__ __launch_bounds__(64) void fused1w_kernel(
    const float* __restrict__ X, const float* __restrict__ E,
    const u16* __restrict__ Wfrag, const float* __restrict__ bprime,
    int T, u16* __restrict__ Sg, float* __restrict__ Eg)
{
  __shared__ __align__(16) uint2 lds8[4096];  // 32 KB: 32 matrices x 128 fp8-chunks
  int l = threadIdx.x, tc = l & 31, h = l >> 5;

  short8 wf[32];
#pragma unroll
  for (int it = 0; it < 32; ++it)
    wf[it] = *(const short8*)(Wfrag + ((size_t)it * 64 + l) * 8);

  f32x16 acc, zero16;
#pragma unroll
  for (int r = 0; r < 16; ++r) {
    int row = (r & 3) + 8 * (r >> 2) + 4 * h;
    acc[r]  = (row == tc) ? 1.f : 0.f;
    zero16[r] = 0.f;
  }
  float Eacc = 0.f;

  for (int grp = 0; grp < 2; ++grp) {
    int tglob = blockIdx.x * 64 + grp * 32 + tc;

    // ---- Phase P: production (verified math; fp8 pack; swizzled b64 writes) ----
    float4 xa = *(const float4*)(X + (size_t)tglob * 16 + 8 * h);
    float4 xb = *(const float4*)(X + (size_t)tglob * 16 + 8 * h + 4);
    u32 xp0, xp1, xp2, xp3;
    asm("v_cvt_pk_bf16_f32 %0, %1, %2" : "=v"(xp0) : "v"(xa.x), "v"(xa.y));
    asm("v_cvt_pk_bf16_f32 %0, %1, %2" : "=v"(xp1) : "v"(xa.z), "v"(xa.w));
    asm("v_cvt_pk_bf16_f32 %0, %1, %2" : "=v"(xp2) : "v"(xb.x), "v"(xb.y));
    asm("v_cvt_pk_bf16_f32 %0, %1, %2" : "=v"(xp3) : "v"(xb.z), "v"(xb.w));
    uint4 xu = make_uint4(xp0, xp1, xp2, xp3);
    short8 xf = __builtin_bit_cast(short8, xu);

    float ee[16];
#pragma unroll
    for (int qd = 0; qd < 4; ++qd) {
      float4 eq = *(const float4*)(E + (size_t)tglob * 32 + 4 * h + 8 * qd);
      ee[4*qd+0] = eq.x * 128.f; ee[4*qd+1] = eq.y * 128.f;   // 2^7 staging scale
      ee[4*qd+2] = eq.z * 128.f; ee[4*qd+3] = eq.w * 128.f;
    }

#pragma unroll
    for (int b = 0; b < 4; ++b) {
      u32 q1[16], q2[16];
      bmat2_batch_fp8(wf + 8*b,     8*b,     xf, bprime, h, ee, tglob, q1);  // i lo half
      bmat2_batch_fp8(wf + 8*b + 4, 8*b + 4, xf, bprime, h, ee, tglob, q2);  // i hi half
#pragma unroll
      for (int r = 0; r < 16; ++r) {
        int j = 4*h + 8*(r>>2) + (r&3);
        int c = (j + 32 * (b & 1)) * 2 + (b >> 1);      // verified chunk index
        lds8[tc * 128 + (c ^ (tc & 15))] = make_uint2(q1[r], q2[r]);
      }
    }
    __syncthreads();

    // ---- Phase C: chain the 32 matrices (prefetched A; dual independent MFMA) ----
    uint2 c0 = lds8[(2 * l) ^ 0];
    uint2 c1 = lds8[(2 * l + 1) ^ 0];
    uint4 A1u = fp8x8_to_bf16x8(c0);
    uint4 A2u = fp8x8_to_bf16x8(c1);
#pragma unroll 4
    for (int k = 0; k < 32; ++k) {
      uint4 nA1 = A1u, nA2 = A2u;
      if (k < 31) {
        int kn = k + 1, s = kn & 15;
        uint2 d0 = lds8[kn * 128 + ((2 * l)     ^ s)];
        uint2 d1 = lds8[kn * 128 + ((2 * l + 1) ^ s)];
        nA1 = fp8x8_to_bf16x8(d0);
        nA2 = fp8x8_to_bf16x8(d1);
      }
      uint4 B1, B2;
      acc_to_bops(acc, B1, B2);
      f32x16 t1 = __builtin_amdgcn_mfma_f32_32x32x16_bf16(
          __builtin_bit_cast(short8, A1u), __builtin_bit_cast(short8, B1), zero16, 0, 0, 0);
      f32x16 t2 = __builtin_amdgcn_mfma_f32_32x32x16_bf16(
          __builtin_bit_cast(short8, A2u), __builtin_bit_cast(short8, B2), zero16, 0, 0, 0);
#pragma unroll
      for (int r = 0; r < 16; ++r) acc[r] = t1[r] + t2[r];
      if ((k & 7) == 7) renorm(acc, Eacc);
      A1u = nA1; A2u = nA2;
    }
    __syncthreads();  // before next group's production overwrites LDS
  }

  // ---- epilogue: verbatim verified out_frags write ----
  int col = l & 31;
#pragma unroll
  for (int r = 0; r < 16; ++r) {
    int row = (r & 3) + 8 * (r >> 2) + 4 * h;
    int flat = (row + 32 * ((col >> 3) & 1)) * 16 + ((col >> 4) << 3) + (col & 7);
    Sg[(size_t)blockIdx.x * 1024 + flat] = f2bf(acc[r]);
  }
  if (l == 0) Eg[blockIdx.x] = Eacc;
}

// ---------------------------------------------------------------------------
// Chain kernel (levels 2-3; verified multi-wave form, matrix-major bf16).
// ---------------------------------------------------------------------------
__global__ void chain_kernel(
    const uint4* __restrict__ in_frags, const float* __restrict__ in_E,
    int nchains, int mpb, u16* __restrict__ out_frags,
    float* __restrict__ out_E, float* __restrict__ out_final)
{
  int w = threadIdx.x >> 6, l = threadIdx.x & 63;
  int cid = blockIdx.x * (blockDim.x >> 6) + w;
  if (cid >= nchains) return;

  long base = (long)cid * mpb;
  const uint4* pA = in_frags + (size_t)(2 * l) + (size_t)base * 128;
  const uint4* pB = pA + 1;

  uint4 bufA[8], bufB[8];
#pragma unroll
  for (int u = 0; u < 8; ++u) {
    bufA[u] = pA[(size_t)u * 128];
    bufB[u] = pB[(size_t)u * 128];
  }

  int col = l & 31, h = l >> 5;
  f32x16 acc, zero16;
#pragma unroll
  for (int r = 0; r < 16; ++r) {
    int row = (r & 3) + 8 * (r >> 2) + 4 * h;
    acc[r]  = (row == col) ? 1.f : 0.f;
    zero16[r] = 0.f;
  }

  float Eacc = 0.f;
  if (in_E) {
    for (int k = 0; k < mpb; ++k) Eacc += in_E[base + k];
  }

  for (int s = 0; s < mpb; s += 8) {
#pragma unroll
    for (int u = 0; u < 8; ++u) {
      uint4 B1, B2;
      acc_to_bops(acc, B1, B2);
      short8 A1 = __builtin_bit_cast(short8, bufA[u]);
      short8 A2 = __builtin_bit_cast(short8, bufB[u]);
      int nm = s + u + 8;
      if (nm < mpb) {
        bufA[u] = pA[(size_t)nm * 128];
        bufB[u] = pB[(size_t)nm * 128];
      }
      f32x16 t1 = __builtin_amdgcn_mfma_f32_32x32x16_bf16(
          A1, __builtin_bit_cast(short8, B1), zero16, 0, 0, 0);
      acc = __builtin_amdgcn_mfma_f32_32x32x16_bf16(
          A2, __builtin_bit_cast(short8, B2), t1, 0, 0, 0);
    }
    renorm(acc, Eacc);
  }

  if (out_final) {
#pragma unroll
    for (int r = 0; r < 16; ++r) {
      int row = (r & 3) + 8 * (r >> 2) + 4 * h;
      out_final[row * 32 + col] = acc[r];
    }
    if (l == 0) *out_E = Eacc;
  } else {
#pragma unroll
    for (int r = 0; r < 16; ++r) {
      int row = (r & 3) + 8 * (r >> 2) + 4 * h;
      int flat = (row + 32 * ((col >> 3) & 1)) * 16 + ((col >> 4) << 3) + (col & 7);
      out_frags[(size_t)cid * 1024 + flat] = f2bf(acc[r]);
    }
    if (l == 0) out_E[cid] = Eacc;
  }
}

// ---------------------------------------------------------------------------
// finalize: removes the 2^7 staging scale exactly: Egrand_true = Egrand - 7*T.
// ---------------------------------------------------------------------------
__global__ __launch_bounds__(64) void finalize_kernel(
    const float* __restrict__ init_logits, const float* __restrict__ E,
    const float* __restrict__ Spart, int nSpart,
    const float* __restrict__ MT, const float* __restrict__ Egrand,
    long Tcount, float* __restrict__ out)
{
  int l = threadIdx.x;
  int j = l & 31;

  float il = init_logits[j];
  float mx = il;
#pragma unroll
  for (int m = 16; m >= 1; m >>= 1) mx = fmaxf(mx, __shfl_xor(mx, m, 32));
  float pz = __expf(il - mx);
  float sz = pz;
#pragma unroll
  for (int m = 16; m >= 1; m >>= 1) sz += __shfl_xor(sz, m, 32);
  float a0 = (pz / sz) * E[j];

  float rbuf[32];
  const float4* rowp = (const float4*)(MT + j * 32);
#pragma unroll
  for (int q = 0; q < 8; ++q) {
    float4 v = rowp[q];
    rbuf[4*q+0] = v.x; rbuf[4*q+1] = v.y; rbuf[4*q+2] = v.z; rbuf[4*q+3] = v.w;
  }
  float af = 0.f;
#pragma unroll
  for (int m = 0; m < 32; ++m) af = fmaf(__shfl(a0, m, 32), rbuf[m], af);

  float sa = af;
#pragma unroll
  for (int m = 16; m >= 1; m >>= 1) sa += __shfl_xor(sa, m, 32);

  double ss = 0.0;
  for (int idx = l; idx < nSpart; idx += 64) ss += (double)Spart[idx];
#pragma unroll
  for (int m = 32; m >= 1; m >>= 1) ss += __shfl_xor(ss, m, 64);

  if (l == 0) {
    double eg = (double)(*Egrand) - 7.0 * (double)Tcount;  // remove staging scale
    double r = log((double)sa) + ss + 0.6931471805599453 * eg;
    out[0] = (float)r;
  }
}

// ---------------------------------------------------------------------------
extern "C" void kernel_launch(void* const* d_in, const int* in_sizes, int n_in,
                              void* d_out, int out_size, void* d_ws, size_t ws_size,
                              hipStream_t stream) {
  const float* X   = (const float*)d_in[0];
  const float* Y   = (const float*)d_in[1];
  const float* il  = (const float*)d_in[2];
  const float* W   = (const float*)d_in[3];
  const float* b   = (const float*)d_in[4];
  const float* mu  = (const float*)d_in[5];
  const float* rlv = (const float*)d_in[6];
  float* out = (float*)d_out;

  int T   = in_sizes[0] / 16;
  int NB0 = (T + 63) / 64;
  int NC  = T / 64;   // L1 chains (2048 @ T=131072) — exact r5/r8 structure

  char* ws = (char*)d_ws;
  size_t off = 0;
  auto alloc = [&](size_t bytes) -> void* {
    void* p = ws + off;
    off = (off + bytes + 255) & ~(size_t)255;
    return p;
  };
  float* E      = (float*)alloc((size_t)T * 32 * 4);
  float* Spart  = (float*)alloc((size_t)NB0 * 4);
  u16*   Sg     = (u16*)  alloc((size_t)NC * 2048);
  float* Eg     = (float*)alloc((size_t)NC * 4);
  u16*   Rf     = (u16*)  alloc((size_t)64 * 2048);
  float* ER     = (float*)alloc((size_t)64 * 4);
  float* MT     = (float*)alloc(4096);
  float* Egrand = (float*)alloc(256);
  u16*   Wfrag  = (u16*)  alloc((size_t)16384 * 2);
  float* bprime = (float*)alloc((size_t)1024 * 4);

  prep_kernel<<<64, 256, 0, stream>>>(W, b, Wfrag, bprime);
  emis_kernel<<<NB0, 256, 0, stream>>>(Y, mu, rlv, T, E, Spart);

  // Fused: B-production + L1 chain, one wave per block, scaled-fp8 LDS staging.
  fused1w_kernel<<<NC, 64, 0, stream>>>(X, E, Wfrag, bprime, T, Sg, Eg);

  // L2: 64 chains of 32 over Sg; L3: 1 chain of 64 (exact r5/r8 structure).
  chain_kernel<<<16, 256, 0, stream>>>((const uint4*)Sg, Eg, 64, NC / 64, Rf, ER, nullptr);
  chain_kernel<<<1, 64, 0, stream>>>((const uint4*)Rf, ER, 1, 64, nullptr, Egrand, MT);

  finalize_kernel<<<1, 64, 0, stream>>>(il, E, Spart, NB0, MT, Egrand, (long)T, out);
}

// Round 13
// 148.671 us; speedup vs baseline: 1.0475x; 1.0475x over previous
//
#include <hip/hip_runtime.h>

typedef float  f32x16 __attribute__((ext_vector_type(16)));
typedef float  f32x2  __attribute__((ext_vector_type(2)));
typedef short  short8 __attribute__((ext_vector_type(8)));
typedef unsigned short u16;
typedef unsigned int   u32;

#define LOG2PI_F 1.8378770664093453f

__device__ __forceinline__ u16 f2bf(float f) {
  u32 u = __builtin_bit_cast(u32, f);
  u32 r = (u + 0x7FFFu + ((u >> 16) & 1u)) >> 16;
  return (u16)r;
}

// ---------------------------------------------------------------------------
// K0: emissions. E[t,j] = exp(log_em[t,j] - s_t), s_t = max_j log_em[t,j].
// ---------------------------------------------------------------------------
__global__ __launch_bounds__(256) void emis_kernel(
    const float* __restrict__ Y, const float* __restrict__ mu,
    const float* __restrict__ rlv, int T,
    float* __restrict__ E, float* __restrict__ Spart)
{
  int j  = threadIdx.x & 31;
  int ts = threadIdx.x >> 5;  // 0..7

  float muv[16], iv[16];
  float slv = 0.f;
  const float4* mp = (const float4*)(mu  + (size_t)j * 16);
  const float4* rp = (const float4*)(rlv + (size_t)j * 16);
#pragma unroll
  for (int q = 0; q < 4; ++q) {
    float4 m4 = mp[q], r4 = rp[q];
    float mm[4] = {m4.x, m4.y, m4.z, m4.w};
    float rr[4] = {r4.x, r4.y, r4.z, r4.w};
#pragma unroll
    for (int e = 0; e < 4; ++e) {
      float lv = fminf(fmaxf(rr[e], -6.f), 6.f);
      muv[4*q+e] = mm[e];
      iv[4*q+e]  = __expf(-lv);
      slv += lv;
    }
  }
  float base_c = 16.f * LOG2PI_F + slv;

  float sacc = 0.f;
  for (int p2 = 0; p2 < 8; ++p2) {
    int t = blockIdx.x * 64 + p2 * 8 + ts;
    if (t < T) {
      float quad = 0.f;
      const float4* yp = (const float4*)(Y + (size_t)t * 16);
#pragma unroll
      for (int q = 0; q < 4; ++q) {
        float4 y4 = yp[q];
        float yy[4] = {y4.x, y4.y, y4.z, y4.w};
#pragma unroll
        for (int e = 0; e < 4; ++e) {
          float d = yy[e] - muv[4*q+e];
          quad = fmaf(d * d, iv[4*q+e], quad);
        }
      }
      float lem = -0.5f * (base_c + quad);
      float mx = lem;
#pragma unroll
      for (int m = 16; m >= 1; m >>= 1) mx = fmaxf(mx, __shfl_xor(mx, m, 32));
      E[(size_t)t * 32 + j] = __expf(lem - mx);
      if (j == 0) sacc += mx;
    }
  }
  __shared__ float sred[8];
  if (j == 0) sred[ts] = sacc;
  __syncthreads();
  if (threadIdx.x == 0) {
    float s = 0.f;
#pragma unroll
    for (int k = 0; k < 8; ++k) s += sred[k];
    Spart[blockIdx.x] = s;
  }
}

// ---------------------------------------------------------------------------
// Prep: Wfrag = A-operand fragments of W/ln2 (bf16), bprime = b/ln2.
// ---------------------------------------------------------------------------
__global__ __launch_bounds__(256) void prep_kernel(
    const float* __restrict__ W, const float* __restrict__ b,
    u16* __restrict__ Wfrag, float* __restrict__ bprime)
{
  const float INVLN2 = 1.4426950408889634f;
  int idx = blockIdx.x * 256 + threadIdx.x;
  if (idx < 16384) {
    int i = idx >> 9, rem = idx & 511, l = rem >> 3, e = rem & 7;
    int j = l & 31, h = l >> 5;
    Wfrag[idx] = f2bf(W[i * 512 + j * 16 + h * 8 + e] * INVLN2);
  }
  if (idx < 1024) bprime[idx] = b[idx] * INVLN2;
}

// ---------------------------------------------------------------------------
// Shared primitives (hardware-verified rounds 0-11).
// ---------------------------------------------------------------------------
__device__ __forceinline__ void acc_to_bops(const f32x16& acc, uint4& B1, uint4& B2) {
  u32 pk[8];
#pragma unroll
  for (int q = 0; q < 8; ++q) {
    u32 r;
    asm("v_cvt_pk_bf16_f32 %0, %1, %2" : "=v"(r) : "v"(acc[2*q]), "v"(acc[2*q+1]));
    pk[q] = r;
  }
  asm("v_permlane32_swap_b32 %0, %1" : "+v"(pk[0]), "+v"(pk[2]));
  asm("v_permlane32_swap_b32 %0, %1" : "+v"(pk[1]), "+v"(pk[3]));
  B1 = make_uint4(pk[0], pk[1], pk[2], pk[3]);
  asm("v_permlane32_swap_b32 %0, %1" : "+v"(pk[4]), "+v"(pk[6]));
  asm("v_permlane32_swap_b32 %0, %1" : "+v"(pk[5]), "+v"(pk[7]));
  B2 = make_uint4(pk[4], pk[5], pk[6], pk[7]);
}

__device__ __forceinline__ void renorm(f32x16& acc, float& Eacc) {
  float m = acc[0];
#pragma unroll
  for (int r = 1; r < 16; ++r) m = fmaxf(m, acc[r]);
#pragma unroll
  for (int off = 32; off >= 1; off >>= 1) m = fmaxf(m, __shfl_xor(m, off, 64));
  if (m > 0.f) {
    int ex;
    frexpf(m, &ex);
    float sc = ldexpf(1.f, -ex);
#pragma unroll
    for (int r = 0; r < 16; ++r) acc[r] *= sc;
    Eacc += (float)ex;
  }
}

// fp8 chunk (8 e4m3 bytes in a uint2) -> 8 bf16 (uint4), byte order preserved.
__device__ __forceinline__ uint4 fp8x8_to_bf16x8(uint2 c) {
  f32x2 l0 = __builtin_amdgcn_cvt_pk_f32_fp8((int)c.x, false);
  f32x2 h0 = __builtin_amdgcn_cvt_pk_f32_fp8((int)c.x, true);
  f32x2 l1 = __builtin_amdgcn_cvt_pk_f32_fp8((int)c.y, false);
  f32x2 h1 = __builtin_amdgcn_cvt_pk_f32_fp8((int)c.y, true);
  u32 w0, w1, w2, w3;
  asm("v_cvt_pk_bf16_f32 %0, %1, %2" : "=v"(w0) : "v"(l0.x), "v"(l0.y));
  asm("v_cvt_pk_bf16_f32 %0, %1, %2" : "=v"(w1) : "v"(h0.x), "v"(h0.y));
  asm("v_cvt_pk_bf16_f32 %0, %1, %2" : "=v"(w2) : "v"(l1.x), "v"(l1.y));
  asm("v_cvt_pk_bf16_f32 %0, %1, %2" : "=v"(w3) : "v"(h1.x), "v"(h1.y));
  return make_uint4(w0, w1, w2, w3);
}

// ---------------------------------------------------------------------------
// Production batch (verified math), output packed fp8 SCALED BY 2^7:
// q[r] = 4 e4m3 bytes = 128*B[t=tc][i=ib0..ib0+3][j(r,h)]. The 2^7 per-matrix
// scale is absorbed by the chain's power-of-2 renorm into Eacc and removed
// once in finalize (Egrand - 7*T). ee[] arrives pre-scaled by 128.
// ---------------------------------------------------------------------------
__device__ __forceinline__ void bmat2_batch_fp8(
    const short8* wf, int ib0, short8 xf, const float* __restrict__ bprime,
    int h, const float* ee, int tglob, u32* q /* [16] */)
{
  f32x16 a[4];
#pragma unroll
  for (int e = 0; e < 4; ++e) {
    f32x16 c;
#pragma unroll
    for (int qd = 0; qd < 4; ++qd) {
      float4 b4 = *(const float4*)(bprime + (ib0 + e) * 32 + 4 * h + 8 * qd);
      c[4*qd+0] = b4.x; c[4*qd+1] = b4.y; c[4*qd+2] = b4.z; c[4*qd+3] = b4.w;
    }
    a[e] = __builtin_amdgcn_mfma_f32_32x32x16_bf16(wf[e], xf, c, 0, 0, 0);
  }
#pragma unroll
  for (int e = 0; e < 4; ++e) {
#pragma unroll
    for (int r = 0; r < 16; ++r) a[e][r] = exp2f(a[e][r]);
    float s = (((a[e][0] + a[e][1]) + (a[e][2] + a[e][3])) +
               ((a[e][4] + a[e][5]) + (a[e][6] + a[e][7]))) +
              (((a[e][8] + a[e][9]) + (a[e][10] + a[e][11])) +
               ((a[e][12] + a[e][13]) + (a[e][14] + a[e][15])));
    float s2 = s, s3 = s;
    asm("v_permlane32_swap_b32 %0, %1" : "+v"(s2), "+v"(s3));
    float rv = __builtin_amdgcn_rcpf(s2 + s3);
#pragma unroll
    for (int r = 0; r < 16; ++r) a[e][r] *= rv;
  }
#pragma unroll
  for (int r = 0; r < 16; ++r) {
    float e0 = a[0][r] * ee[r], e1 = a[1][r] * ee[r];
    float e2 = a[2][r] * ee[r], e3 = a[3][r] * ee[r];
    if (tglob == 0) {
      int j = 4 * h + 8 * (r >> 2) + (r & 3);
      e0 = (ib0 + 0 == j) ? 128.f : 0.f;   // scaled identity, exact in e4m3
      e1 = (ib0 + 1 == j) ? 128.f : 0.f;
      e2 = (ib0 + 2 == j) ? 128.f : 0.f;
      e3 = (ib0 + 3 == j) ? 128.f : 0.f;
    }
    u32 v = (u32)__builtin_amdgcn_cvt_pk_fp8_f32(e0, e1, 0, false);
    v = (u32)__builtin_amdgcn_cvt_pk_fp8_f32(e2, e3, (int)v, true);
    q[r] = v;
  }
}

// ---------------------------------------------------------------------------
// fused1w: ONE WAVE per block, block owns 64 t. fp8 staging (32KB, 2^7 scale,
// XOR swizzle c^(matrix&15)). Chain phase: TWO independent interleaved
// 16-step sub-chains per group (S_a: matrices 0-15, S_b: 16-31) — halves the
// serial dependency depth; the wave always has a second chain to issue during
// MFMA/LDS stalls. Combine S = S_b*S_a via the verified epilogue transform
// (S_b -> A-frag bf16 in consumed LDS slot 0) + one verified step on acc_a.
// Exponents add; acc_b resets to identity. Ordering == verified hierarchy.
// ---------------------------------------------------------------------------
__global__ __launch_bounds__(64) void fused1w_kernel(
    const float* __restrict__ X, const float* __restrict__ E,
    const u16* __restrict__ Wfrag, const float* __restrict__ bprime,
    int T, u16* __restrict__ Sg, float* __restrict__ Eg)
{
  __shared__ __align__(16) uint2 lds8[4096];  // 32 KB: 32 matrices x 128 fp8-chunks
  int l = threadIdx.x, tc = l & 31, h = l >> 5;

  short8 wf[32];
#pragma unroll
  for (int it = 0; it < 32; ++it)
    wf[it] = *(const short8*)(Wfrag + ((size_t)it * 64 + l) * 8);

  f32x16 acc, accb, zero16;
#pragma unroll
  for (int r = 0; r < 16; ++r) {
    int row = (r & 3) + 8 * (r >> 2) + 4 * h;
    acc[r]  = (row == tc) ? 1.f : 0.f;
    accb[r] = (row == tc) ? 1.f : 0.f;
    zero16[r] = 0.f;
  }
  float Eacc = 0.f, Eaccb = 0.f;

  for (int grp = 0; grp < 2; ++grp) {
    int tglob = blockIdx.x * 64 + grp * 32 + tc;

    // ---- Phase P: production (verified math; fp8 pack; swizzled b64 writes) ----
    float4 xa = *(const float4*)(X + (size_t)tglob * 16 + 8 * h);
    float4 xb = *(const float4*)(X + (size_t)tglob * 16 + 8 * h + 4);
    u32 xp0, xp1, xp2, xp3;
    asm("v_cvt_pk_bf16_f32 %0, %1, %2" : "=v"(xp0) : "v"(xa.x), "v"(xa.y));
    asm("v_cvt_pk_bf16_f32 %0, %1, %2" : "=v"(xp1) : "v"(xa.z), "v"(xa.w));
    asm("v_cvt_pk_bf16_f32 %0, %1, %2" : "=v"(xp2) : "v"(xb.x), "v"(xb.y));
    asm("v_cvt_pk_bf16_f32 %0, %1, %2" : "=v"(xp3) : "v"(xb.z), "v"(xb.w));
    uint4 xu = make_uint4(xp0, xp1, xp2, xp3);
    short8 xf = __builtin_bit_cast(short8, xu);

    float ee[16];
#pragma unroll
    for (int qd = 0; qd < 4; ++qd) {
      float4 eq = *(const float4*)(E + (size_t)tglob * 32 + 4 * h + 8 * qd);
      ee[4*qd+0] = eq.x * 128.f; ee[4*qd+1] = eq.y * 128.f;   // 2^7 staging scale
      ee[4*qd+2] = eq.z * 128.f; ee[4*qd+3] = eq.w * 128.f;
    }

#pragma unroll
    for (int b = 0; b < 4; ++b) {
      u32 q1[16], q2[16];
      bmat2_batch_fp8(wf + 8*b,     8*b,     xf, bprime, h, ee, tglob, q1);  // i lo half
      bmat2_batch_fp8(wf + 8*b + 4, 8*b + 4, xf, bprime, h, ee, tglob, q2);  // i hi half
#pragma unroll
      for (int r = 0; r < 16; ++r) {
        int j = 4*h + 8*(r>>2) + (r&3);
        int c = (j + 32 * (b & 1)) * 2 + (b >> 1);      // verified chunk index
        lds8[tc * 128 + (c ^ (tc & 15))] = make_uint2(q1[r], q2[r]);
      }
    }
    __syncthreads();

    // ---- Phase C: dual interleaved 16-step sub-chains ----
#pragma unroll 4
    for (int k = 0; k < 16; ++k) {
      int sa = k & 15, kb = 16 + k, sb = kb & 15;
      uint2 a0 = lds8[k  * 128 + ((2 * l)     ^ sa)];
      uint2 a1 = lds8[k  * 128 + ((2 * l + 1) ^ sa)];
      uint2 b0 = lds8[kb * 128 + ((2 * l)     ^ sb)];
      uint2 b1 = lds8[kb * 128 + ((2 * l + 1) ^ sb)];
      uint4 Aa1 = fp8x8_to_bf16x8(a0), Aa2 = fp8x8_to_bf16x8(a1);
      uint4 Ab1 = fp8x8_to_bf16x8(b0), Ab2 = fp8x8_to_bf16x8(b1);
      uint4 B1a, B2a, B1b, B2b;
      acc_to_bops(acc,  B1a, B2a);
      acc_to_bops(accb, B1b, B2b);
      f32x16 t1a = __builtin_amdgcn_mfma_f32_32x32x16_bf16(
          __builtin_bit_cast(short8, Aa1), __builtin_bit_cast(short8, B1a), zero16, 0, 0, 0);
      f32x16 t1b = __builtin_amdgcn_mfma_f32_32x32x16_bf16(
          __builtin_bit_cast(short8, Ab1), __builtin_bit_cast(short8, B1b), zero16, 0, 0, 0);
      acc = __builtin_amdgcn_mfma_f32_32x32x16_bf16(
          __builtin_bit_cast(short8, Aa2), __builtin_bit_cast(short8, B2a), t1a, 0, 0, 0);
      accb = __builtin_amdgcn_mfma_f32_32x32x16_bf16(
          __builtin_bit_cast(short8, Ab2), __builtin_bit_cast(short8, B2b), t1b, 0, 0, 0);
      if ((k & 7) == 7) { renorm(acc, Eacc); renorm(accb, Eaccb); }
    }

    // ---- Combine: acc <- S_b * S_a via epilogue transform + one step ----
    __syncthreads();   // all staged-matrix reads complete
    {
      u16* sc = (u16*)lds8;   // reuse consumed slots 0-1 (2KB scratch)
#pragma unroll
      for (int r = 0; r < 16; ++r) {
        int row = (r & 3) + 8 * (r >> 2) + 4 * h;
        int flat = (row + 32 * ((tc >> 3) & 1)) * 16 + ((tc >> 4) << 3) + (tc & 7);
        sc[flat] = f2bf(accb[r]);
      }
      __syncthreads();
      const uint4* sp = (const uint4*)lds8;
      uint4 A1 = sp[2 * l], A2 = sp[2 * l + 1];
      uint4 B1, B2;
      acc_to_bops(acc, B1, B2);
      f32x16 t1 = __builtin_amdgcn_mfma_f32_32x32x16_bf16(
          __builtin_bit_cast(short8, A1), __builtin_bit_cast(short8, B1), zero16, 0, 0, 0);
      acc = __builtin_amdgcn_mfma_f32_32x32x16_bf16(
          __builtin_bit_cast(short8, A2), __builtin_bit_cast(short8, B2), t1, 0, 0, 0);
      Eacc += Eaccb;
      Eaccb = 0.f;
#pragma unroll
      for (int r = 0; r < 16; ++r) {
        int row = (r & 3) + 8 * (r >> 2) + 4 * h;
        accb[r] = (row == tc) ? 1.f : 0.f;
      }
    }
    __syncthreads();  // before next group's production overwrites LDS
  }

  // ---- epilogue: verbatim verified out_frags write ----
  int col = l & 31;
#pragma unroll
  for (int r = 0; r < 16; ++r) {
    int row = (r & 3) + 8 * (r >> 2) + 4 * h;
    int flat = (row + 32 * ((col >> 3) & 1)) * 16 + ((col >> 4) << 3) + (col & 7);
    Sg[(size_t)blockIdx.x * 1024 + flat] = f2bf(acc[r]);
  }
  if (l == 0) Eg[blockIdx.x] = Eacc;
}

// ---------------------------------------------------------------------------
// Chain kernel (levels 2-3; verified multi-wave form, matrix-major bf16).
// ---------------------------------------------------------------------------
__global__ void chain_kernel(
    const uint4* __restrict__ in_frags, const float* __restrict__ in_E,
    int nchains, int mpb, u16* __restrict__ out_frags,
    float* __restrict__ out_E, float* __restrict__ out_final)
{
  int w = threadIdx.x >> 6, l = threadIdx.x & 63;
  int cid = blockIdx.x * (blockDim.x >> 6) + w;
  if (cid >= nchains) return;

  long base = (long)cid * mpb;
  const uint4* pA = in_frags + (size_t)(2 * l) + (size_t)base * 128;
  const uint4* pB = pA + 1;

  uint4 bufA[8], bufB[8];
#pragma unroll
  for (int u = 0; u < 8; ++u) {
    bufA[u] = pA[(size_t)u * 128];
    bufB[u] = pB[(size_t)u * 128];
  }

  int col = l & 31, h = l >> 5;
  f32x16 acc, zero16;
#pragma unroll
  for (int r = 0; r < 16; ++r) {
    int row = (r & 3) + 8 * (r >> 2) + 4 * h;
    acc[r]  = (row == col) ? 1.f : 0.f;
    zero16[r] = 0.f;
  }

  float Eacc = 0.f;
  if (in_E) {
    for (int k = 0; k < mpb; ++k) Eacc += in_E[base + k];
  }

  for (int s = 0; s < mpb; s += 8) {
#pragma unroll
    for (int u = 0; u < 8; ++u) {
      uint4 B1, B2;
      acc_to_bops(acc, B1, B2);
      short8 A1 = __builtin_bit_cast(short8, bufA[u]);
      short8 A2 = __builtin_bit_cast(short8, bufB[u]);
      int nm = s + u + 8;
      if (nm < mpb) {
        bufA[u] = pA[(size_t)nm * 128];
        bufB[u] = pB[(size_t)nm * 128];
      }
      f32x16 t1 = __builtin_amdgcn_mfma_f32_32x32x16_bf16(
          A1, __builtin_bit_cast(short8, B1), zero16, 0, 0, 0);
      acc = __builtin_amdgcn_mfma_f32_32x32x16_bf16(
          A2, __builtin_bit_cast(short8, B2), t1, 0, 0, 0);
    }
    renorm(acc, Eacc);
  }

  if (out_final) {
#pragma unroll
    for (int r = 0; r < 16; ++r) {
      int row = (r & 3) + 8 * (r >> 2) + 4 * h;
      out_final[row * 32 + col] = acc[r];
    }
    if (l == 0) *out_E = Eacc;
  } else {
#pragma unroll
    for (int r = 0; r < 16; ++r) {
      int row = (r & 3) + 8 * (r >> 2) + 4 * h;
      int flat = (row + 32 * ((col >> 3) & 1)) * 16 + ((col >> 4) << 3) + (col & 7);
      out_frags[(size_t)cid * 1024 + flat] = f2bf(acc[r]);
    }
    if (l == 0) out_E[cid] = Eacc;
  }
}

// ---------------------------------------------------------------------------
// finalize: removes the 2^7 staging scale exactly: Egrand_true = Egrand - 7*T.
// ---------------------------------------------------------------------------
__global__ __launch_bounds__(64) void finalize_kernel(
    const float* __restrict__ init_logits, const float* __restrict__ E,
    const float* __restrict__ Spart, int nSpart,
    const float* __restrict__ MT, const float* __restrict__ Egrand,
    long Tcount, float* __restrict__ out)
{
  int l = threadIdx.x;
  int j = l & 31;

  float il = init_logits[j];
  float mx = il;
#pragma unroll
  for (int m = 16; m >= 1; m >>= 1) mx = fmaxf(mx, __shfl_xor(mx, m, 32));
  float pz = __expf(il - mx);
  float sz = pz;
#pragma unroll
  for (int m = 16; m >= 1; m >>= 1) sz += __shfl_xor(sz, m, 32);
  float a0 = (pz / sz) * E[j];

  float rbuf[32];
  const float4* rowp = (const float4*)(MT + j * 32);
#pragma unroll
  for (int q = 0; q < 8; ++q) {
    float4 v = rowp[q];
    rbuf[4*q+0] = v.x; rbuf[4*q+1] = v.y; rbuf[4*q+2] = v.z; rbuf[4*q+3] = v.w;
  }
  float af = 0.f;
#pragma unroll
  for (int m = 0; m < 32; ++m) af = fmaf(__shfl(a0, m, 32), rbuf[m], af);

  float sa = af;
#pragma unroll
  for (int m = 16; m >= 1; m >>= 1) sa += __shfl_xor(sa, m, 32);

  double ss = 0.0;
  for (int idx = l; idx < nSpart; idx += 64) ss += (double)Spart[idx];
#pragma unroll
  for (int m = 32; m >= 1; m >>= 1) ss += __shfl_xor(ss, m, 64);

  if (l == 0) {
    double eg = (double)(*Egrand) - 7.0 * (double)Tcount;  // remove staging scale
    double r = log((double)sa) + ss + 0.6931471805599453 * eg;
    out[0] = (float)r;
  }
}

// ---------------------------------------------------------------------------
extern "C" void kernel_launch(void* const* d_in, const int* in_sizes, int n_in,
                              void* d_out, int out_size, void* d_ws, size_t ws_size,
                              hipStream_t stream) {
  const float* X   = (const float*)d_in[0];
  const float* Y   = (const float*)d_in[1];
  const float* il  = (const float*)d_in[2];
  const float* W   = (const float*)d_in[3];
  const float* b   = (const float*)d_in[4];
  const float* mu  = (const float*)d_in[5];
  const float* rlv = (const float*)d_in[6];
  float* out = (float*)d_out;

  int T   = in_sizes[0] / 16;
  int NB0 = (T + 63) / 64;
  int NC  = T / 64;   // L1 chains (2048 @ T=131072)

  char* ws = (char*)d_ws;
  size_t off = 0;
  auto alloc = [&](size_t bytes) -> void* {
    void* p = ws + off;
    off = (off + bytes + 255) & ~(size_t)255;
    return p;
  };
  float* E      = (float*)alloc((size_t)T * 32 * 4);
  float* Spart  = (float*)alloc((size_t)NB0 * 4);
  u16*   Sg     = (u16*)  alloc((size_t)NC * 2048);
  float* Eg     = (float*)alloc((size_t)NC * 4);
  u16*   Rf     = (u16*)  alloc((size_t)64 * 2048);
  float* ER     = (float*)alloc((size_t)64 * 4);
  float* MT     = (float*)alloc(4096);
  float* Egrand = (float*)alloc(256);
  u16*   Wfrag  = (u16*)  alloc((size_t)16384 * 2);
  float* bprime = (float*)alloc((size_t)1024 * 4);

  prep_kernel<<<64, 256, 0, stream>>>(W, b, Wfrag, bprime);
  emis_kernel<<<NB0, 256, 0, stream>>>(Y, mu, rlv, T, E, Spart);

  // Fused: B-production + L1 chain (dual interleaved sub-chains), fp8 staging.
  fused1w_kernel<<<NC, 64, 0, stream>>>(X, E, Wfrag, bprime, T, Sg, Eg);

  // L2: 64 chains of 32 over Sg; L3: 1 chain of 64.
  chain_kernel<<<16, 256, 0, stream>>>((const uint4*)Sg, Eg, 64, NC / 64, Rf, ER, nullptr);
  chain_kernel<<<1, 64, 0, stream>>>((const uint4*)Rf, ER, 1, 64, nullptr, Egrand, MT);

  finalize_kernel<<<1, 64, 0, stream>>>(il, E, Spart, NB0, MT, Egrand, (long)T, out);
}

// Round 14
// 127.585 us; speedup vs baseline: 1.2206x; 1.1653x over previous
//
#include <hip/hip_runtime.h>

typedef float  f32x16 __attribute__((ext_vector_type(16)));
typedef float  f32x2  __attribute__((ext_vector_type(2)));
typedef short  short8 __attribute__((ext_vector_type(8)));
typedef unsigned short u16;
typedef unsigned int   u32;

#define LOG2PI_F 1.8378770664093453f

__device__ __forceinline__ u16 f2bf(float f) {
  u32 u = __builtin_bit_cast(u32, f);
  u32 r = (u + 0x7FFFu + ((u >> 16) & 1u)) >> 16;
  return (u16)r;
}

// ---------------------------------------------------------------------------
// K0: emissions. E[t,j] = exp(log_em[t,j] - s_t), s_t = max_j log_em[t,j].
// ---------------------------------------------------------------------------
__global__ __launch_bounds__(256) void emis_kernel(
    const float* __restrict__ Y, const float* __restrict__ mu,
    const float* __restrict__ rlv, int T,
    float* __restrict__ E, float* __restrict__ Spart)
{
  int j  = threadIdx.x & 31;
  int ts = threadIdx.x >> 5;  // 0..7

  float muv[16], iv[16];
  float slv = 0.f;
  const float4* mp = (const float4*)(mu  + (size_t)j * 16);
  const float4* rp = (const float4*)(rlv + (size_t)j * 16);
#pragma unroll
  for (int q = 0; q < 4; ++q) {
    float4 m4 = mp[q], r4 = rp[q];
    float mm[4] = {m4.x, m4.y, m4.z, m4.w};
    float rr[4] = {r4.x, r4.y, r4.z, r4.w};
#pragma unroll
    for (int e = 0; e < 4; ++e) {
      float lv = fminf(fmaxf(rr[e], -6.f), 6.f);
      muv[4*q+e] = mm[e];
      iv[4*q+e]  = __expf(-lv);
      slv += lv;
    }
  }
  float base_c = 16.f * LOG2PI_F + slv;

  float sacc = 0.f;
  for (int p2 = 0; p2 < 8; ++p2) {
    int t = blockIdx.x * 64 + p2 * 8 + ts;
    if (t < T) {
      float quad = 0.f;
      const float4* yp = (const float4*)(Y + (size_t)t * 16);
#pragma unroll
      for (int q = 0; q < 4; ++q) {
        float4 y4 = yp[q];
        float yy[4] = {y4.x, y4.y, y4.z, y4.w};
#pragma unroll
        for (int e = 0; e < 4; ++e) {
          float d = yy[e] - muv[4*q+e];
          quad = fmaf(d * d, iv[4*q+e], quad);
        }
      }
      float lem = -0.5f * (base_c + quad);
      float mx = lem;
#pragma unroll
      for (int m = 16; m >= 1; m >>= 1) mx = fmaxf(mx, __shfl_xor(mx, m, 32));
      E[(size_t)t * 32 + j] = __expf(lem - mx);
      if (j == 0) sacc += mx;
    }
  }
  __shared__ float sred[8];
  if (j == 0) sred[ts] = sacc;
  __syncthreads();
  if (threadIdx.x == 0) {
    float s = 0.f;
#pragma unroll
    for (int k = 0; k < 8; ++k) s += sred[k];
    Spart[blockIdx.x] = s;
  }
}

// ---------------------------------------------------------------------------
// Prep: Wfrag = A-operand fragments of W/ln2 (bf16), bprime = b/ln2.
// ---------------------------------------------------------------------------
__global__ __launch_bounds__(256) void prep_kernel(
    const float* __restrict__ W, const float* __restrict__ b,
    u16* __restrict__ Wfrag, float* __restrict__ bprime)
{
  const float INVLN2 = 1.4426950408889634f;
  int idx = blockIdx.x * 256 + threadIdx.x;
  if (idx < 16384) {
    int i = idx >> 9, rem = idx & 511, l = rem >> 3, e = rem & 7;
    int j = l & 31, h = l >> 5;
    Wfrag[idx] = f2bf(W[i * 512 + j * 16 + h * 8 + e] * INVLN2);
  }
  if (idx < 1024) bprime[idx] = b[idx] * INVLN2;
}

// ---------------------------------------------------------------------------
// Shared primitives (hardware-verified rounds 0-13).
// ---------------------------------------------------------------------------
__device__ __forceinline__ void acc_to_bops(const f32x16& acc, uint4& B1, uint4& B2) {
  u32 pk[8];
#pragma unroll
  for (int q = 0; q < 8; ++q) {
    u32 r;
    asm("v_cvt_pk_bf16_f32 %0, %1, %2" : "=v"(r) : "v"(acc[2*q]), "v"(acc[2*q+1]));
    pk[q] = r;
  }
  asm("v_permlane32_swap_b32 %0, %1" : "+v"(pk[0]), "+v"(pk[2]));
  asm("v_permlane32_swap_b32 %0, %1" : "+v"(pk[1]), "+v"(pk[3]));
  B1 = make_uint4(pk[0], pk[1], pk[2], pk[3]);
  asm("v_permlane32_swap_b32 %0, %1" : "+v"(pk[4]), "+v"(pk[6]));
  asm("v_permlane32_swap_b32 %0, %1" : "+v"(pk[5]), "+v"(pk[7]));
  B2 = make_uint4(pk[4], pk[5], pk[6], pk[7]);
}

// renorm: scale acc by 2^-ex (ex from the wave-max exponent), accumulate ex.
// m is always positive & normal here (entries positive; bounded growth between
// renorms) -> frexpf/ldexpf replaced by exact exponent bit-twiddle.
__device__ __forceinline__ void renorm(f32x16& acc, float& Eacc) {
  float m0 = fmaxf(fmaxf(fmaxf(acc[0], acc[1]),  fmaxf(acc[2], acc[3])),
                   fmaxf(fmaxf(acc[4], acc[5]),  fmaxf(acc[6], acc[7])));
  float m1 = fmaxf(fmaxf(fmaxf(acc[8], acc[9]),  fmaxf(acc[10], acc[11])),
                   fmaxf(fmaxf(acc[12], acc[13]), fmaxf(acc[14], acc[15])));
  float m = fmaxf(m0, m1);
#pragma unroll
  for (int off = 32; off >= 1; off >>= 1) m = fmaxf(m, __shfl_xor(m, off, 64));
  u32 be = (__builtin_bit_cast(u32, m) >> 23) & 0xFFu;       // biased exponent
  float sc = __builtin_bit_cast(float, (253u - be) << 23);   // = 2^(126-be) = 2^-ex
  Eacc += (float)((int)be - 126);                            // ex, frexp semantics
#pragma unroll
  for (int r = 0; r < 16; ++r) acc[r] *= sc;
}

// fp8 chunk (8 e4m3 bytes in a uint2) -> 8 bf16 (uint4), byte order preserved.
__device__ __forceinline__ uint4 fp8x8_to_bf16x8(uint2 c) {
  f32x2 l0 = __builtin_amdgcn_cvt_pk_f32_fp8((int)c.x, false);
  f32x2 h0 = __builtin_amdgcn_cvt_pk_f32_fp8((int)c.x, true);
  f32x2 l1 = __builtin_amdgcn_cvt_pk_f32_fp8((int)c.y, false);
  f32x2 h1 = __builtin_amdgcn_cvt_pk_f32_fp8((int)c.y, true);
  u32 w0, w1, w2, w3;
  asm("v_cvt_pk_bf16_f32 %0, %1, %2" : "=v"(w0) : "v"(l0.x), "v"(l0.y));
  asm("v_cvt_pk_bf16_f32 %0, %1, %2" : "=v"(w1) : "v"(h0.x), "v"(h0.y));
  asm("v_cvt_pk_bf16_f32 %0, %1, %2" : "=v"(w2) : "v"(l1.x), "v"(l1.y));
  asm("v_cvt_pk_bf16_f32 %0, %1, %2" : "=v"(w3) : "v"(h1.x), "v"(h1.y));
  return make_uint4(w0, w1, w2, w3);
}

// ---------------------------------------------------------------------------
// Production batch (verified math), output packed fp8 SCALED BY 2^7:
// q[r] = 4 e4m3 bytes = 128*B[t=tc][i=ib0..ib0+3][j(r,h)]. The 2^7 per-matrix
// scale is absorbed by the chain's power-of-2 renorm into Eacc and removed
// once in finalize (Egrand - 7*T). ee[] arrives pre-scaled by 128.
// exp2 via native v_exp_f32 (inputs bounded, no edge cases). Sum = depth-4 tree.
// ---------------------------------------------------------------------------
__device__ __forceinline__ void bmat2_batch_fp8(
    const short8* wf, int ib0, short8 xf, const float* __restrict__ bprime,
    int h, const float* ee, int tglob, u32* q /* [16] */)
{
  f32x16 a[4];
#pragma unroll
  for (int e = 0; e < 4; ++e) {
    f32x16 c;
#pragma unroll
    for (int qd = 0; qd < 4; ++qd) {
      float4 b4 = *(const float4*)(bprime + (ib0 + e) * 32 + 4 * h + 8 * qd);
      c[4*qd+0] = b4.x; c[4*qd+1] = b4.y; c[4*qd+2] = b4.z; c[4*qd+3] = b4.w;
    }
    a[e] = __builtin_amdgcn_mfma_f32_32x32x16_bf16(wf[e], xf, c, 0, 0, 0);
  }
#pragma unroll
  for (int e = 0; e < 4; ++e) {
#pragma unroll
    for (int r = 0; r < 16; ++r) a[e][r] = __builtin_amdgcn_exp2f(a[e][r]);
    float s = (((a[e][0] + a[e][1]) + (a[e][2] + a[e][3])) +
               ((a[e][4] + a[e][5]) + (a[e][6] + a[e][7]))) +
              (((a[e][8] + a[e][9]) + (a[e][10] + a[e][11])) +
               ((a[e][12] + a[e][13]) + (a[e][14] + a[e][15])));
    float s2 = s, s3 = s;
    asm("v_permlane32_swap_b32 %0, %1" : "+v"(s2), "+v"(s3));
    float rv = __builtin_amdgcn_rcpf(s2 + s3);
#pragma unroll
    for (int r = 0; r < 16; ++r) a[e][r] *= rv;
  }
#pragma unroll
  for (int r = 0; r < 16; ++r) {
    float e0 = a[0][r] * ee[r], e1 = a[1][r] * ee[r];
    float e2 = a[2][r] * ee[r], e3 = a[3][r] * ee[r];
    if (tglob == 0) {
      int j = 4 * h + 8 * (r >> 2) + (r & 3);
      e0 = (ib0 + 0 == j) ? 128.f : 0.f;   // scaled identity, exact in e4m3
      e1 = (ib0 + 1 == j) ? 128.f : 0.f;
      e2 = (ib0 + 2 == j) ? 128.f : 0.f;
      e3 = (ib0 + 3 == j) ? 128.f : 0.f;
    }
    u32 v = (u32)__builtin_amdgcn_cvt_pk_fp8_f32(e0, e1, 0, false);
    v = (u32)__builtin_amdgcn_cvt_pk_fp8_f32(e2, e3, (int)v, true);
    q[r] = v;
  }
}

// ---------------------------------------------------------------------------
// fused1w: ONE WAVE per block (green r11 structure), block owns 64 t.
// fp8 staging (32KB, 2^7 scale, XOR swizzle c^(matrix&15)); simple chain
// (verified serial MFMA pair), native exp2 + bit-twiddle renorm.
// ---------------------------------------------------------------------------
__global__ __launch_bounds__(64) void fused1w_kernel(
    const float* __restrict__ X, const float* __restrict__ E,
    const u16* __restrict__ Wfrag, const float* __restrict__ bprime,
    int T, u16* __restrict__ Sg, float* __restrict__ Eg)
{
  __shared__ __align__(16) uint2 lds8[4096];  // 32 KB: 32 matrices x 128 fp8-chunks
  int l = threadIdx.x, tc = l & 31, h = l >> 5;

  short8 wf[32];
#pragma unroll
  for (int it = 0; it < 32; ++it)
    wf[it] = *(const short8*)(Wfrag + ((size_t)it * 64 + l) * 8);

  f32x16 acc, zero16;
#pragma unroll
  for (int r = 0; r < 16; ++r) {
    int row = (r & 3) + 8 * (r >> 2) + 4 * h;
    acc[r]  = (row == tc) ? 1.f : 0.f;
    zero16[r] = 0.f;
  }
  float Eacc = 0.f;

  for (int grp = 0; grp < 2; ++grp) {
    int tglob = blockIdx.x * 64 + grp * 32 + tc;

    // ---- Phase P: production (verified math; fp8 pack; swizzled b64 writes) ----
    float4 xa = *(const float4*)(X + (size_t)tglob * 16 + 8 * h);
    float4 xb = *(const float4*)(X + (size_t)tglob * 16 + 8 * h + 4);
    u32 xp0, xp1, xp2, xp3;
    asm("v_cvt_pk_bf16_f32 %0, %1, %2" : "=v"(xp0) : "v"(xa.x), "v"(xa.y));
    asm("v_cvt_pk_bf16_f32 %0, %1, %2" : "=v"(xp1) : "v"(xa.z), "v"(xa.w));
    asm("v_cvt_pk_bf16_f32 %0, %1, %2" : "=v"(xp2) : "v"(xb.x), "v"(xb.y));
    asm("v_cvt_pk_bf16_f32 %0, %1, %2" : "=v"(xp3) : "v"(xb.z), "v"(xb.w));
    uint4 xu = make_uint4(xp0, xp1, xp2, xp3);
    short8 xf = __builtin_bit_cast(short8, xu);

    float ee[16];
#pragma unroll
    for (int qd = 0; qd < 4; ++qd) {
      float4 eq = *(const float4*)(E + (size_t)tglob * 32 + 4 * h + 8 * qd);
      ee[4*qd+0] = eq.x * 128.f; ee[4*qd+1] = eq.y * 128.f;   // 2^7 staging scale
      ee[4*qd+2] = eq.z * 128.f; ee[4*qd+3] = eq.w * 128.f;
    }

#pragma unroll
    for (int b = 0; b < 4; ++b) {
      u32 q1[16], q2[16];
      bmat2_batch_fp8(wf + 8*b,     8*b,     xf, bprime, h, ee, tglob, q1);  // i lo half
      bmat2_batch_fp8(wf + 8*b + 4, 8*b + 4, xf, bprime, h, ee, tglob, q2);  // i hi half
#pragma unroll
      for (int r = 0; r < 16; ++r) {
        int j = 4*h + 8*(r>>2) + (r&3);
        int c = (j + 32 * (b & 1)) * 2 + (b >> 1);      // verified chunk index
        lds8[tc * 128 + (c ^ (tc & 15))] = make_uint2(q1[r], q2[r]);
      }
    }
    __syncthreads();

    // ---- Phase C: chain the 32 matrices (verbatim green step; fp8 upconvert) ----
#pragma unroll 4
    for (int k = 0; k < 32; ++k) {
      int s = k & 15;
      uint2 c0 = lds8[k * 128 + ((2 * l)     ^ s)];
      uint2 c1 = lds8[k * 128 + ((2 * l + 1) ^ s)];
      uint4 A1u = fp8x8_to_bf16x8(c0);
      uint4 A2u = fp8x8_to_bf16x8(c1);
      uint4 B1, B2;
      acc_to_bops(acc, B1, B2);
      f32x16 t1 = __builtin_amdgcn_mfma_f32_32x32x16_bf16(
          __builtin_bit_cast(short8, A1u), __builtin_bit_cast(short8, B1), zero16, 0, 0, 0);
      acc = __builtin_amdgcn_mfma_f32_32x32x16_bf16(
          __builtin_bit_cast(short8, A2u), __builtin_bit_cast(short8, B2), t1, 0, 0, 0);
      if ((k & 7) == 7) renorm(acc, Eacc);
    }
    __syncthreads();  // before next group's production overwrites LDS
  }

  // ---- epilogue: verbatim verified out_frags write ----
  int col = l & 31;
#pragma unroll
  for (int r = 0; r < 16; ++r) {
    int row = (r & 3) + 8 * (r >> 2) + 4 * h;
    int flat = (row + 32 * ((col >> 3) & 1)) * 16 + ((col >> 4) << 3) + (col & 7);
    Sg[(size_t)blockIdx.x * 1024 + flat] = f2bf(acc[r]);
  }
  if (l == 0) Eg[blockIdx.x] = Eacc;
}

// ---------------------------------------------------------------------------
// Chain kernel (levels 2-3; verified multi-wave form, matrix-major bf16).
// ---------------------------------------------------------------------------
__global__ void chain_kernel(
    const uint4* __restrict__ in_frags, const float* __restrict__ in_E,
    int nchains, int mpb, u16* __restrict__ out_frags,
    float* __restrict__ out_E, float* __restrict__ out_final)
{
  int w = threadIdx.x >> 6, l = threadIdx.x & 63;
  int cid = blockIdx.x * (blockDim.x >> 6) + w;
  if (cid >= nchains) return;

  long base = (long)cid * mpb;
  const uint4* pA = in_frags + (size_t)(2 * l) + (size_t)base * 128;
  const uint4* pB = pA + 1;

  uint4 bufA[8], bufB[8];
#pragma unroll
  for (int u = 0; u < 8; ++u) {
    bufA[u] = pA[(size_t)u * 128];
    bufB[u] = pB[(size_t)u * 128];
  }

  int col = l & 31, h = l >> 5;
  f32x16 acc, zero16;
#pragma unroll
  for (int r = 0; r < 16; ++r) {
    int row = (r & 3) + 8 * (r >> 2) + 4 * h;
    acc[r]  = (row == col) ? 1.f : 0.f;
    zero16[r] = 0.f;
  }

  float Eacc = 0.f;
  if (in_E) {
    for (int k = 0; k < mpb; ++k) Eacc += in_E[base + k];
  }

  for (int s = 0; s < mpb; s += 8) {
#pragma unroll
    for (int u = 0; u < 8; ++u) {
      uint4 B1, B2;
      acc_to_bops(acc, B1, B2);
      short8 A1 = __builtin_bit_cast(short8, bufA[u]);
      short8 A2 = __builtin_bit_cast(short8, bufB[u]);
      int nm = s + u + 8;
      if (nm < mpb) {
        bufA[u] = pA[(size_t)nm * 128];
        bufB[u] = pB[(size_t)nm * 128];
      }
      f32x16 t1 = __builtin_amdgcn_mfma_f32_32x32x16_bf16(
          A1, __builtin_bit_cast(short8, B1), zero16, 0, 0, 0);
      acc = __builtin_amdgcn_mfma_f32_32x32x16_bf16(
          A2, __builtin_bit_cast(short8, B2), t1, 0, 0, 0);
    }
    renorm(acc, Eacc);
  }

  if (out_final) {
#pragma unroll
    for (int r = 0; r < 16; ++r) {
      int row = (r & 3) + 8 * (r >> 2) + 4 * h;
      out_final[row * 32 + col] = acc[r];
    }
    if (l == 0) *out_E = Eacc;
  } else {
#pragma unroll
    for (int r = 0; r < 16; ++r) {
      int row = (r & 3) + 8 * (r >> 2) + 4 * h;
      int flat = (row + 32 * ((col >> 3) & 1)) * 16 + ((col >> 4) << 3) + (col & 7);
      out_frags[(size_t)cid * 1024 + flat] = f2bf(acc[r]);
    }
    if (l == 0) out_E[cid] = Eacc;
  }
}

// ---------------------------------------------------------------------------
// finalize: removes the 2^7 staging scale exactly: Egrand_true = Egrand - 7*T.
// ---------------------------------------------------------------------------
__global__ __launch_bounds__(64) void finalize_kernel(
    const float* __restrict__ init_logits, const float* __restrict__ E,
    const float* __restrict__ Spart, int nSpart,
    const float* __restrict__ MT, const float* __restrict__ Egrand,
    long Tcount, float* __restrict__ out)
{
  int l = threadIdx.x;
  int j = l & 31;

  float il = init_logits[j];
  float mx = il;
#pragma unroll
  for (int m = 16; m >= 1; m >>= 1) mx = fmaxf(mx, __shfl_xor(mx, m, 32));
  float pz = __expf(il - mx);
  float sz = pz;
#pragma unroll
  for (int m = 16; m >= 1; m >>= 1) sz += __shfl_xor(sz, m, 32);
  float a0 = (pz / sz) * E[j];

  float rbuf[32];
  const float4* rowp = (const float4*)(MT + j * 32);
#pragma unroll
  for (int q = 0; q < 8; ++q) {
    float4 v = rowp[q];
    rbuf[4*q+0] = v.x; rbuf[4*q+1] = v.y; rbuf[4*q+2] = v.z; rbuf[4*q+3] = v.w;
  }
  float af = 0.f;
#pragma unroll
  for (int m = 0; m < 32; ++m) af = fmaf(__shfl(a0, m, 32), rbuf[m], af);

  float sa = af;
#pragma unroll
  for (int m = 16; m >= 1; m >>= 1) sa += __shfl_xor(sa, m, 32);

  double ss = 0.0;
  for (int idx = l; idx < nSpart; idx += 64) ss += (double)Spart[idx];
#pragma unroll
  for (int m = 32; m >= 1; m >>= 1) ss += __shfl_xor(ss, m, 64);

  if (l == 0) {
    double eg = (double)(*Egrand) - 7.0 * (double)Tcount;  // remove staging scale
    double r = log((double)sa) + ss + 0.6931471805599453 * eg;
    out[0] = (float)r;
  }
}

// ---------------------------------------------------------------------------
extern "C" void kernel_launch(void* const* d_in, const int* in_sizes, int n_in,
                              void* d_out, int out_size, void* d_ws, size_t ws_size,
                              hipStream_t stream) {
  const float* X   = (const float*)d_in[0];
  const float* Y   = (const float*)d_in[1];
  const float* il  = (const float*)d_in[2];
  const float* W   = (const float*)d_in[3];
  const float* b   = (const float*)d_in[4];
  const float* mu  = (const float*)d_in[5];
  const float* rlv = (const float*)d_in[6];
  float* out = (float*)d_out;

  int T   = in_sizes[0] / 16;
  int NB0 = (T + 63) / 64;
  int NC  = T / 64;   // L1 chains (2048 @ T=131072)

  char* ws = (char*)d_ws;
  size_t off = 0;
  auto alloc = [&](size_t bytes) -> void* {
    void* p = ws + off;
    off = (off + bytes + 255) & ~(size_t)255;
    return p;
  };
  float* E      = (float*)alloc((size_t)T * 32 * 4);
  float* Spart  = (float*)alloc((size_t)NB0 * 4);
  u16*   Sg     = (u16*)  alloc((size_t)NC * 2048);
  float* Eg     = (float*)alloc((size_t)NC * 4);
  u16*   Rf     = (u16*)  alloc((size_t)64 * 2048);
  float* ER     = (float*)alloc((size_t)64 * 4);
  float* MT     = (float*)alloc(4096);
  float* Egrand = (float*)alloc(256);
  u16*   Wfrag  = (u16*)  alloc((size_t)16384 * 2);
  float* bprime = (float*)alloc((size_t)1024 * 4);

  prep_kernel<<<64, 256, 0, stream>>>(W, b, Wfrag, bprime);
  emis_kernel<<<NB0, 256, 0, stream>>>(Y, mu, rlv, T, E, Spart);

  // Fused: B-production + L1 chain, one wave per block, scaled-fp8 LDS staging.
  fused1w_kernel<<<NC, 64, 0, stream>>>(X, E, Wfrag, bprime, T, Sg, Eg);

  // L2: 64 chains of 32 over Sg; L3: 1 chain of 64.
  chain_kernel<<<16, 256, 0, stream>>>((const uint4*)Sg, Eg, 64, NC / 64, Rf, ER, nullptr);
  chain_kernel<<<1, 64, 0, stream>>>((const uint4*)Rf, ER, 1, 64, nullptr, Egrand, MT);

  finalize_kernel<<<1, 64, 0, stream>>>(il, E, Spart, NB0, MT, Egrand, (long)T, out);
}

// Round 15
// 117.911 us; speedup vs baseline: 1.3207x; 1.0820x over previous
//
#include <hip/hip_runtime.h>

typedef float  f32x16 __attribute__((ext_vector_type(16)));
typedef float  f32x2  __attribute__((ext_vector_type(2)));
typedef short  short8 __attribute__((ext_vector_type(8)));
typedef unsigned short u16;
typedef unsigned int   u32;

#define LOG2PI_F 1.8378770664093453f

__device__ __forceinline__ u16 f2bf(float f) {
  u32 u = __builtin_bit_cast(u32, f);
  u32 r = (u + 0x7FFFu + ((u >> 16) & 1u)) >> 16;
  return (u16)r;
}

// ---------------------------------------------------------------------------
// K0: emissions (+ prep folded into blocks 0..63).
// E[t,j] = exp(log_em[t,j] - s_t), s_t = max_j log_em[t,j].
// Wfrag = A-operand fragments of W/ln2 (bf16), bprime = b/ln2.
// ---------------------------------------------------------------------------
__global__ __launch_bounds__(256) void emis_kernel(
    const float* __restrict__ Y, const float* __restrict__ mu,
    const float* __restrict__ rlv, int T,
    float* __restrict__ E, float* __restrict__ Spart,
    const float* __restrict__ W, const float* __restrict__ b,
    u16* __restrict__ Wfrag, float* __restrict__ bprime)
{
  int j  = threadIdx.x & 31;
  int ts = threadIdx.x >> 5;  // 0..7

  float muv[16], iv[16];
  float slv = 0.f;
  const float4* mp = (const float4*)(mu  + (size_t)j * 16);
  const float4* rp = (const float4*)(rlv + (size_t)j * 16);
#pragma unroll
  for (int q = 0; q < 4; ++q) {
    float4 m4 = mp[q], r4 = rp[q];
    float mm[4] = {m4.x, m4.y, m4.z, m4.w};
    float rr[4] = {r4.x, r4.y, r4.z, r4.w};
#pragma unroll
    for (int e = 0; e < 4; ++e) {
      float lv = fminf(fmaxf(rr[e], -6.f), 6.f);
      muv[4*q+e] = mm[e];
      iv[4*q+e]  = __expf(-lv);
      slv += lv;
    }
  }
  float base_c = 16.f * LOG2PI_F + slv;

  float sacc = 0.f;
  for (int p2 = 0; p2 < 8; ++p2) {
    int t = blockIdx.x * 64 + p2 * 8 + ts;
    if (t < T) {
      float quad = 0.f;
      const float4* yp = (const float4*)(Y + (size_t)t * 16);
#pragma unroll
      for (int q = 0; q < 4; ++q) {
        float4 y4 = yp[q];
        float yy[4] = {y4.x, y4.y, y4.z, y4.w};
#pragma unroll
        for (int e = 0; e < 4; ++e) {
          float d = yy[e] - muv[4*q+e];
          quad = fmaf(d * d, iv[4*q+e], quad);
        }
      }
      float lem = -0.5f * (base_c + quad);
      float mx = lem;
#pragma unroll
      for (int m = 16; m >= 1; m >>= 1) mx = fmaxf(mx, __shfl_xor(mx, m, 32));
      E[(size_t)t * 32 + j] = __expf(lem - mx);
      if (j == 0) sacc += mx;
    }
  }
  __shared__ float sred[8];
  if (j == 0) sred[ts] = sacc;
  __syncthreads();
  if (threadIdx.x == 0) {
    float s = 0.f;
#pragma unroll
    for (int k = 0; k < 8; ++k) s += sred[k];
    Spart[blockIdx.x] = s;
  }

  // ---- prep (blocks 0..63): Wfrag + bprime ----
  if (blockIdx.x < 64) {
    const float INVLN2 = 1.4426950408889634f;
    int idx = blockIdx.x * 256 + threadIdx.x;
    {
      int i = idx >> 9, rem = idx & 511, l = rem >> 3, e = rem & 7;
      int jj = l & 31, h = l >> 5;
      Wfrag[idx] = f2bf(W[i * 512 + jj * 16 + h * 8 + e] * INVLN2);
    }
    if (idx < 1024) bprime[idx] = b[idx] * INVLN2;
  }
}

// ---------------------------------------------------------------------------
// Shared primitives (hardware-verified rounds 0-14).
// ---------------------------------------------------------------------------
__device__ __forceinline__ void acc_to_bops(const f32x16& acc, uint4& B1, uint4& B2) {
  u32 pk[8];
#pragma unroll
  for (int q = 0; q < 8; ++q) {
    u32 r;
    asm("v_cvt_pk_bf16_f32 %0, %1, %2" : "=v"(r) : "v"(acc[2*q]), "v"(acc[2*q+1]));
    pk[q] = r;
  }
  asm("v_permlane32_swap_b32 %0, %1" : "+v"(pk[0]), "+v"(pk[2]));
  asm("v_permlane32_swap_b32 %0, %1" : "+v"(pk[1]), "+v"(pk[3]));
  B1 = make_uint4(pk[0], pk[1], pk[2], pk[3]);
  asm("v_permlane32_swap_b32 %0, %1" : "+v"(pk[4]), "+v"(pk[6]));
  asm("v_permlane32_swap_b32 %0, %1" : "+v"(pk[5]), "+v"(pk[7]));
  B2 = make_uint4(pk[4], pk[5], pk[6], pk[7]);
}

// renorm: exact exponent bit-twiddle (m always positive & normal here).
__device__ __forceinline__ void renorm(f32x16& acc, float& Eacc) {
  float m0 = fmaxf(fmaxf(fmaxf(acc[0], acc[1]),  fmaxf(acc[2], acc[3])),
                   fmaxf(fmaxf(acc[4], acc[5]),  fmaxf(acc[6], acc[7])));
  float m1 = fmaxf(fmaxf(fmaxf(acc[8], acc[9]),  fmaxf(acc[10], acc[11])),
                   fmaxf(fmaxf(acc[12], acc[13]), fmaxf(acc[14], acc[15])));
  float m = fmaxf(m0, m1);
#pragma unroll
  for (int off = 32; off >= 1; off >>= 1) m = fmaxf(m, __shfl_xor(m, off, 64));
  u32 be = (__builtin_bit_cast(u32, m) >> 23) & 0xFFu;       // biased exponent
  float sc = __builtin_bit_cast(float, (253u - be) << 23);   // 2^(126-be) = 2^-ex
  Eacc += (float)((int)be - 126);                            // frexp semantics
#pragma unroll
  for (int r = 0; r < 16; ++r) acc[r] *= sc;
}

// fp8 chunk (8 e4m3 bytes in a uint2) -> 8 bf16 (uint4), byte order preserved.
__device__ __forceinline__ uint4 fp8x8_to_bf16x8(uint2 c) {
  f32x2 l0 = __builtin_amdgcn_cvt_pk_f32_fp8((int)c.x, false);
  f32x2 h0 = __builtin_amdgcn_cvt_pk_f32_fp8((int)c.x, true);
  f32x2 l1 = __builtin_amdgcn_cvt_pk_f32_fp8((int)c.y, false);
  f32x2 h1 = __builtin_amdgcn_cvt_pk_f32_fp8((int)c.y, true);
  u32 w0, w1, w2, w3;
  asm("v_cvt_pk_bf16_f32 %0, %1, %2" : "=v"(w0) : "v"(l0.x), "v"(l0.y));
  asm("v_cvt_pk_bf16_f32 %0, %1, %2" : "=v"(w1) : "v"(h0.x), "v"(h0.y));
  asm("v_cvt_pk_bf16_f32 %0, %1, %2" : "=v"(w2) : "v"(l1.x), "v"(l1.y));
  asm("v_cvt_pk_bf16_f32 %0, %1, %2" : "=v"(w3) : "v"(h1.x), "v"(h1.y));
  return make_uint4(w0, w1, w2, w3);
}

// ---------------------------------------------------------------------------
// Production batch (verified math), output packed fp8 SCALED BY 2^7.
// ee[] arrives pre-scaled by 128; identity override for tglob==0 exact.
// ---------------------------------------------------------------------------
__device__ __forceinline__ void bmat2_batch_fp8(
    const short8* wf, int ib0, short8 xf, const float* __restrict__ bprime,
    int h, const float* ee, int tglob, u32* q /* [16] */)
{
  f32x16 a[4];
#pragma unroll
  for (int e = 0; e < 4; ++e) {
    f32x16 c;
#pragma unroll
    for (int qd = 0; qd < 4; ++qd) {
      float4 b4 = *(const float4*)(bprime + (ib0 + e) * 32 + 4 * h + 8 * qd);
      c[4*qd+0] = b4.x; c[4*qd+1] = b4.y; c[4*qd+2] = b4.z; c[4*qd+3] = b4.w;
    }
    a[e] = __builtin_amdgcn_mfma_f32_32x32x16_bf16(wf[e], xf, c, 0, 0, 0);
  }
#pragma unroll
  for (int e = 0; e < 4; ++e) {
#pragma unroll
    for (int r = 0; r < 16; ++r) a[e][r] = __builtin_amdgcn_exp2f(a[e][r]);
    float s = (((a[e][0] + a[e][1]) + (a[e][2] + a[e][3])) +
               ((a[e][4] + a[e][5]) + (a[e][6] + a[e][7]))) +
              (((a[e][8] + a[e][9]) + (a[e][10] + a[e][11])) +
               ((a[e][12] + a[e][13]) + (a[e][14] + a[e][15])));
    float s2 = s, s3 = s;
    asm("v_permlane32_swap_b32 %0, %1" : "+v"(s2), "+v"(s3));
    float rv = __builtin_amdgcn_rcpf(s2 + s3);
#pragma unroll
    for (int r = 0; r < 16; ++r) a[e][r] *= rv;
  }
#pragma unroll
  for (int r = 0; r < 16; ++r) {
    float e0 = a[0][r] * ee[r], e1 = a[1][r] * ee[r];
    float e2 = a[2][r] * ee[r], e3 = a[3][r] * ee[r];
    if (tglob == 0) {
      int j = 4 * h + 8 * (r >> 2) + (r & 3);
      e0 = (ib0 + 0 == j) ? 128.f : 0.f;   // scaled identity, exact in e4m3
      e1 = (ib0 + 1 == j) ? 128.f : 0.f;
      e2 = (ib0 + 2 == j) ? 128.f : 0.f;
      e3 = (ib0 + 3 == j) ? 128.f : 0.f;
    }
    u32 v = (u32)__builtin_amdgcn_cvt_pk_fp8_f32(e0, e1, 0, false);
    v = (u32)__builtin_amdgcn_cvt_pk_fp8_f32(e2, e3, (int)v, true);
    q[r] = v;
  }
}

// ---------------------------------------------------------------------------
// fused1w: ONE WAVE per block, block owns 128 t (4 groups of 32 — r15 change:
// halves tail work, amortizes prologue; inner loops byte-identical to r14).
// fp8 staging (32KB, 2^7 scale, XOR swizzle c^(matrix&15)).
// ---------------------------------------------------------------------------
__global__ __launch_bounds__(64) void fused1w_kernel(
    const float* __restrict__ X, const float* __restrict__ E,
    const u16* __restrict__ Wfrag, const float* __restrict__ bprime,
    int T, u16* __restrict__ Sg, float* __restrict__ Eg)
{
  __shared__ __align__(16) uint2 lds8[4096];  // 32 KB: 32 matrices x 128 fp8-chunks
  int l = threadIdx.x, tc = l & 31, h = l >> 5;

  short8 wf[32];
#pragma unroll
  for (int it = 0; it < 32; ++it)
    wf[it] = *(const short8*)(Wfrag + ((size_t)it * 64 + l) * 8);

  f32x16 acc, zero16;
#pragma unroll
  for (int r = 0; r < 16; ++r) {
    int row = (r & 3) + 8 * (r >> 2) + 4 * h;
    acc[r]  = (row == tc) ? 1.f : 0.f;
    zero16[r] = 0.f;
  }
  float Eacc = 0.f;

  for (int grp = 0; grp < 4; ++grp) {
    int tglob = blockIdx.x * 128 + grp * 32 + tc;

    // ---- Phase P: production (verified math; fp8 pack; swizzled b64 writes) ----
    float4 xa = *(const float4*)(X + (size_t)tglob * 16 + 8 * h);
    float4 xb = *(const float4*)(X + (size_t)tglob * 16 + 8 * h + 4);
    u32 xp0, xp1, xp2, xp3;
    asm("v_cvt_pk_bf16_f32 %0, %1, %2" : "=v"(xp0) : "v"(xa.x), "v"(xa.y));
    asm("v_cvt_pk_bf16_f32 %0, %1, %2" : "=v"(xp1) : "v"(xa.z), "v"(xa.w));
    asm("v_cvt_pk_bf16_f32 %0, %1, %2" : "=v"(xp2) : "v"(xb.x), "v"(xb.y));
    asm("v_cvt_pk_bf16_f32 %0, %1, %2" : "=v"(xp3) : "v"(xb.z), "v"(xb.w));
    uint4 xu = make_uint4(xp0, xp1, xp2, xp3);
    short8 xf = __builtin_bit_cast(short8, xu);

    float ee[16];
#pragma unroll
    for (int qd = 0; qd < 4; ++qd) {
      float4 eq = *(const float4*)(E + (size_t)tglob * 32 + 4 * h + 8 * qd);
      ee[4*qd+0] = eq.x * 128.f; ee[4*qd+1] = eq.y * 128.f;   // 2^7 staging scale
      ee[4*qd+2] = eq.z * 128.f; ee[4*qd+3] = eq.w * 128.f;
    }

#pragma unroll
    for (int b = 0; b < 4; ++b) {
      u32 q1[16], q2[16];
      bmat2_batch_fp8(wf + 8*b,     8*b,     xf, bprime, h, ee, tglob, q1);  // i lo half
      bmat2_batch_fp8(wf + 8*b + 4, 8*b + 4, xf, bprime, h, ee, tglob, q2);  // i hi half
#pragma unroll
      for (int r = 0; r < 16; ++r) {
        int j = 4*h + 8*(r>>2) + (r&3);
        int c = (j + 32 * (b & 1)) * 2 + (b >> 1);      // verified chunk index
        lds8[tc * 128 + (c ^ (tc & 15))] = make_uint2(q1[r], q2[r]);
      }
    }
    __syncthreads();

    // ---- Phase C: chain the 32 matrices (verbatim r14 step; fp8 upconvert) ----
#pragma unroll 4
    for (int k = 0; k < 32; ++k) {
      int s = k & 15;
      uint2 c0 = lds8[k * 128 + ((2 * l)     ^ s)];
      uint2 c1 = lds8[k * 128 + ((2 * l + 1) ^ s)];
      uint4 A1u = fp8x8_to_bf16x8(c0);
      uint4 A2u = fp8x8_to_bf16x8(c1);
      uint4 B1, B2;
      acc_to_bops(acc, B1, B2);
      f32x16 t1 = __builtin_amdgcn_mfma_f32_32x32x16_bf16(
          __builtin_bit_cast(short8, A1u), __builtin_bit_cast(short8, B1), zero16, 0, 0, 0);
      acc = __builtin_amdgcn_mfma_f32_32x32x16_bf16(
          __builtin_bit_cast(short8, A2u), __builtin_bit_cast(short8, B2), t1, 0, 0, 0);
      if ((k & 7) == 7) renorm(acc, Eacc);
    }
    __syncthreads();  // before next group's production overwrites LDS
  }

  // ---- epilogue: verbatim verified out_frags write ----
  int col = l & 31;
#pragma unroll
  for (int r = 0; r < 16; ++r) {
    int row = (r & 3) + 8 * (r >> 2) + 4 * h;
    int flat = (row + 32 * ((col >> 3) & 1)) * 16 + ((col >> 4) << 3) + (col & 7);
    Sg[(size_t)blockIdx.x * 1024 + flat] = f2bf(acc[r]);
  }
  if (l == 0) Eg[blockIdx.x] = Eacc;
}

// ---------------------------------------------------------------------------
// Chain kernel (level 2; verified multi-wave form, matrix-major bf16).
// ---------------------------------------------------------------------------
__global__ void chain_kernel(
    const uint4* __restrict__ in_frags, const float* __restrict__ in_E,
    int nchains, int mpb, u16* __restrict__ out_frags,
    float* __restrict__ out_E)
{
  int w = threadIdx.x >> 6, l = threadIdx.x & 63;
  int cid = blockIdx.x * (blockDim.x >> 6) + w;
  if (cid >= nchains) return;

  long base = (long)cid * mpb;
  const uint4* pA = in_frags + (size_t)(2 * l) + (size_t)base * 128;
  const uint4* pB = pA + 1;

  uint4 bufA[8], bufB[8];
#pragma unroll
  for (int u = 0; u < 8; ++u) {
    bufA[u] = pA[(size_t)u * 128];
    bufB[u] = pB[(size_t)u * 128];
  }

  int col = l & 31, h = l >> 5;
  f32x16 acc, zero16;
#pragma unroll
  for (int r = 0; r < 16; ++r) {
    int row = (r & 3) + 8 * (r >> 2) + 4 * h;
    acc[r]  = (row == col) ? 1.f : 0.f;
    zero16[r] = 0.f;
  }

  float Eacc = 0.f;
  if (in_E) {
    for (int k = 0; k < mpb; ++k) Eacc += in_E[base + k];
  }

  for (int s = 0; s < mpb; s += 8) {
#pragma unroll
    for (int u = 0; u < 8; ++u) {
      uint4 B1, B2;
      acc_to_bops(acc, B1, B2);
      short8 A1 = __builtin_bit_cast(short8, bufA[u]);
      short8 A2 = __builtin_bit_cast(short8, bufB[u]);
      int nm = s + u + 8;
      if (nm < mpb) {
        bufA[u] = pA[(size_t)nm * 128];
        bufB[u] = pB[(size_t)nm * 128];
      }
      f32x16 t1 = __builtin_amdgcn_mfma_f32_32x32x16_bf16(
          A1, __builtin_bit_cast(short8, B1), zero16, 0, 0, 0);
      acc = __builtin_amdgcn_mfma_f32_32x32x16_bf16(
          A2, __builtin_bit_cast(short8, B2), t1, 0, 0, 0);
    }
    renorm(acc, Eacc);
  }

#pragma unroll
  for (int r = 0; r < 16; ++r) {
    int row = (r & 3) + 8 * (r >> 2) + 4 * h;
    int flat = (row + 32 * ((col >> 3) & 1)) * 16 + ((col >> 4) << 3) + (col & 7);
    out_frags[(size_t)cid * 1024 + flat] = f2bf(acc[r]);
  }
  if (l == 0) out_E[cid] = Eacc;
}

// ---------------------------------------------------------------------------
// tail: L3 chain (1 wave over Rf, mpb matrices) + finalize, fused.
// sa computed directly from acc C/D registers via the verified row mapping:
// sum over all 64 lanes of sum_r a0[row(r,h)]*acc[r] = sum_{row,col} a0*M.
// out = log(sa) + sum Spart + ln2*(Eacc - 7*T).
// ---------------------------------------------------------------------------
__global__ __launch_bounds__(64) void tail_kernel(
    const uint4* __restrict__ Rf, const float* __restrict__ ER, int mpb,
    const float* __restrict__ init_logits, const float* __restrict__ E,
    const float* __restrict__ Spart, int nSpart, long Tcount,
    float* __restrict__ out)
{
  int l = threadIdx.x, col = l & 31, h = l >> 5;

  // a0[j] = softmax(init)[j] * E[0][j] -> LDS
  __shared__ float a0s[32];
  {
    float il = init_logits[col];
    float mx = il;
#pragma unroll
    for (int m = 16; m >= 1; m >>= 1) mx = fmaxf(mx, __shfl_xor(mx, m, 32));
    float pz = __expf(il - mx);
    float sz = pz;
#pragma unroll
    for (int m = 16; m >= 1; m >>= 1) sz += __shfl_xor(sz, m, 32);
    if (l < 32) a0s[l] = (pz / sz) * E[l];
  }
  __syncthreads();

  // L3 chain over Rf (verbatim verified step, base 0)
  const uint4* pA = Rf + (size_t)(2 * l);
  const uint4* pB = pA + 1;
  uint4 bufA[8], bufB[8];
#pragma unroll
  for (int u = 0; u < 8; ++u) {
    bufA[u] = pA[(size_t)u * 128];
    bufB[u] = pB[(size_t)u * 128];
  }

  f32x16 acc, zero16;
#pragma unroll
  for (int r = 0; r < 16; ++r) {
    int row = (r & 3) + 8 * (r >> 2) + 4 * h;
    acc[r]  = (row == col) ? 1.f : 0.f;
    zero16[r] = 0.f;
  }

  float Eacc = 0.f;
  for (int k = 0; k < mpb; ++k) Eacc += ER[k];

  for (int s = 0; s < mpb; s += 8) {
#pragma unroll
    for (int u = 0; u < 8; ++u) {
      uint4 B1, B2;
      acc_to_bops(acc, B1, B2);
      short8 A1 = __builtin_bit_cast(short8, bufA[u]);
      short8 A2 = __builtin_bit_cast(short8, bufB[u]);
      int nm = s + u + 8;
      if (nm < mpb) {
        bufA[u] = pA[(size_t)nm * 128];
        bufB[u] = pB[(size_t)nm * 128];
      }
      f32x16 t1 = __builtin_amdgcn_mfma_f32_32x32x16_bf16(
          A1, __builtin_bit_cast(short8, B1), zero16, 0, 0, 0);
      acc = __builtin_amdgcn_mfma_f32_32x32x16_bf16(
          A2, __builtin_bit_cast(short8, B2), t1, 0, 0, 0);
    }
    renorm(acc, Eacc);
  }

  // sa = sum over (row,col) of a0[row] * M[row][col]
  float partial = 0.f;
#pragma unroll
  for (int r = 0; r < 16; ++r) {
    int row = (r & 3) + 8 * (r >> 2) + 4 * h;
    partial = fmaf(a0s[row], acc[r], partial);
  }
#pragma unroll
  for (int off = 32; off >= 1; off >>= 1) partial += __shfl_xor(partial, off, 64);

  double ss = 0.0;
  for (int idx = l; idx < nSpart; idx += 64) ss += (double)Spart[idx];
#pragma unroll
  for (int m = 32; m >= 1; m >>= 1) ss += __shfl_xor(ss, m, 64);

  if (l == 0) {
    double eg = (double)Eacc - 7.0 * (double)Tcount;  // remove staging scale
    double r = log((double)partial) + ss + 0.6931471805599453 * eg;
    out[0] = (float)r;
  }
}

// ---------------------------------------------------------------------------
extern "C" void kernel_launch(void* const* d_in, const int* in_sizes, int n_in,
                              void* d_out, int out_size, void* d_ws, size_t ws_size,
                              hipStream_t stream) {
  const float* X   = (const float*)d_in[0];
  const float* Y   = (const float*)d_in[1];
  const float* il  = (const float*)d_in[2];
  const float* W   = (const float*)d_in[3];
  const float* b   = (const float*)d_in[4];
  const float* mu  = (const float*)d_in[5];
  const float* rlv = (const float*)d_in[6];
  float* out = (float*)d_out;

  int T   = in_sizes[0] / 16;
  int NB0 = (T + 63) / 64;
  int NC  = T / 128;   // L1 chains (1024 @ T=131072), 128 t per block

  char* ws = (char*)d_ws;
  size_t off = 0;
  auto alloc = [&](size_t bytes) -> void* {
    void* p = ws + off;
    off = (off + bytes + 255) & ~(size_t)255;
    return p;
  };
  float* E      = (float*)alloc((size_t)T * 32 * 4);
  float* Spart  = (float*)alloc((size_t)NB0 * 4);
  u16*   Sg     = (u16*)  alloc((size_t)NC * 2048);
  float* Eg     = (float*)alloc((size_t)NC * 4);
  u16*   Rf     = (u16*)  alloc((size_t)64 * 2048);
  float* ER     = (float*)alloc((size_t)64 * 4);
  u16*   Wfrag  = (u16*)  alloc((size_t)16384 * 2);
  float* bprime = (float*)alloc((size_t)1024 * 4);

  // emis + prep (merged)
  emis_kernel<<<NB0, 256, 0, stream>>>(Y, mu, rlv, T, E, Spart, W, b, Wfrag, bprime);

  // Fused: B-production + L1 chain (128 t per block), scaled-fp8 LDS staging.
  fused1w_kernel<<<NC, 64, 0, stream>>>(X, E, Wfrag, bprime, T, Sg, Eg);

  // L2: 32 chains of 32 over Sg.
  int nch2 = NC / 32;  // 32
  chain_kernel<<<(nch2 + 3) / 4, 256, 0, stream>>>((const uint4*)Sg, Eg, nch2, 32, Rf, ER);

  // L3 + finalize fused (1 wave, 32 matrices).
  tail_kernel<<<1, 64, 0, stream>>>((const uint4*)Rf, ER, nch2, il, E, Spart, NB0,
                                    (long)T, out);
}